// Round 1
// baseline (232.700 us; speedup 1.0000x reference)
//
#include <hip/hip_runtime.h>

// fbm_dropout: zero columns of an (8192, 4096) fp32 matrix whose grid cell is
// touched by any fiber point of the current epoch.
//
// Grid: n = 64, cell g covers [gx/64 + 1/256, gx/64 + 3/256] per axis.
// Exact-equivalence note: for p in [0,1), u = p*64.0f is exact (power-of-2
// scale), floor(u) exact, and f = u - floor(u) is exact in fp32 (result is a
// multiple of ulp(u) <= 2^-18, < 1). So the reference's
//   x_low <= p && p <= x_high   (bounds exact fp32 values)
// is bit-identical to  0.25f <= f && f <= 0.75f  with cell = (int)floor(u).

#define N_COLS 4096
#define PTS_PER_EPOCH 100
#define N_GRID 64
#define TOTAL_PTS 10000
#define N_FIBERS 64

__global__ void build_mask_kernel(const float* __restrict__ fx,
                                  const float* __restrict__ fy,
                                  const int* __restrict__ epoch_p,
                                  float* __restrict__ mask) {
    const int tid = threadIdx.x;
    // init mask to 1.0 (d_ws is re-poisoned to 0xAA before every launch)
    for (int i = tid; i < N_COLS; i += blockDim.x) mask[i] = 1.0f;
    __syncthreads();

    const int t = epoch_p[0] * PTS_PER_EPOCH;
    const int P = N_FIBERS * PTS_PER_EPOCH;  // 6400 points
    for (int p = tid; p < P; p += blockDim.x) {
        const int f = p / PTS_PER_EPOCH;
        const int j = p - f * PTS_PER_EPOCH;
        const float px = fx[f * TOTAL_PTS + t + j];
        const float py = fy[f * TOTAL_PTS + t + j];
        const float ux = px * 64.0f;
        const float uy = py * 64.0f;
        const float gxf = floorf(ux);
        const float gyf = floorf(uy);
        const float frx = ux - gxf;   // exact
        const float fry = uy - gyf;   // exact
        if (frx >= 0.25f && frx <= 0.75f && fry >= 0.25f && fry <= 0.75f) {
            const int gx = (int)gxf;
            const int gy = (int)gyf;
            if (gx >= 0 && gx < N_GRID && gy >= 0 && gy < N_GRID) {
                mask[gy * N_GRID + gx] = 0.0f;  // racing same-value stores: ok
            }
        }
    }
}

__global__ void apply_mask_kernel(const float4* __restrict__ in4,
                                  const float4* __restrict__ mask4,
                                  float4* __restrict__ out4,
                                  int n4) {
    const int i = blockIdx.x * blockDim.x + threadIdx.x;
    if (i >= n4) return;
    const float4 a = in4[i];
    const float4 m = mask4[i & (N_COLS / 4 - 1)];  // 1024 float4s per row
    float4 r;
    r.x = a.x * m.x;
    r.y = a.y * m.y;
    r.z = a.z * m.z;
    r.w = a.w * m.w;
    out4[i] = r;
}

extern "C" void kernel_launch(void* const* d_in, const int* in_sizes, int n_in,
                              void* d_out, int out_size, void* d_ws, size_t ws_size,
                              hipStream_t stream) {
    const float* inp   = (const float*)d_in[0];   // (8192, 4096) fp32
    const float* fx    = (const float*)d_in[1];   // (64, 10000) fp32
    const float* fy    = (const float*)d_in[2];   // (64, 10000) fp32
    const int*   epoch = (const int*)d_in[3];     // scalar int
    float* out  = (float*)d_out;
    float* mask = (float*)d_ws;                   // 4096 floats = 16 KB

    build_mask_kernel<<<1, 1024, 0, stream>>>(fx, fy, epoch, mask);

    const int n4 = out_size / 4;                  // 8,388,608 float4s
    const int block = 256;
    const int grid = (n4 + block - 1) / block;    // 32768 blocks
    apply_mask_kernel<<<grid, block, 0, stream>>>(
        (const float4*)inp, (const float4*)mask, (float4*)out, n4);
}